// Round 8
// baseline (1280.623 us; speedup 1.0000x reference)
//
#include <hip/hip_runtime.h>
#include <hip/hip_fp16.h>

// ---- problem constants ----
#define Bb 8
#define Ll 4106
#define Cc 768
#define VPT_ 10
#define WSz 14
#define NWIN 25
#define BW_ 200
#define LW_ 206
#define NHh 12
#define HDd 64

typedef _Float16 half8 __attribute__((ext_vector_type(8)));
typedef float floatx4 __attribute__((ext_vector_type(4)));

// async global->LDS, 16 B per lane, wave-uniform LDS base + lane*16
__device__ __forceinline__ void gload16(const _Float16* g, _Float16* l) {
    __builtin_amdgcn_global_load_lds(
        (const __attribute__((address_space(1))) void*)g,
        (__attribute__((address_space(3))) void*)l, 16, 0, 0);
}

// ---------------- fp32 -> fp16 convert ----------------
__global__ void f2h_kernel(const float* __restrict__ in, _Float16* __restrict__ out, int n) {
    int i = blockIdx.x * 256 + threadIdx.x;
    if (i < n) out[i] = (_Float16)in[i];
}

// ---------------- LN1 (contiguous rows, no scatter) ----------------
__global__ __launch_bounds__(256) void ln1_kernel(
    const float* __restrict__ x, const float* __restrict__ w, const float* __restrict__ bia,
    _Float16* __restrict__ xn)
{
    int r = blockIdx.x;
    const float* xr = x + (size_t)r * Cc;
    int t = threadIdx.x;
    float v0 = xr[t], v1 = xr[t + 256], v2 = xr[t + 512];
    float s1 = v0 + v1 + v2;
    float s2 = v0 * v0 + v1 * v1 + v2 * v2;
    #pragma unroll
    for (int off = 32; off > 0; off >>= 1) {
        s1 += __shfl_down(s1, off);
        s2 += __shfl_down(s2, off);
    }
    __shared__ float red[8];
    int wv = t >> 6, ln = t & 63;
    if (ln == 0) { red[wv] = s1; red[4 + wv] = s2; }
    __syncthreads();
    float fs1 = red[0] + red[1] + red[2] + red[3];
    float fs2 = red[4] + red[5] + red[6] + red[7];
    float mean = fs1 * (1.0f / Cc);
    float var  = fs2 * (1.0f / Cc) - mean * mean;
    float rstd = rsqrtf(var + 1e-5f);
    float vv[3] = {v0, v1, v2};
    #pragma unroll
    for (int i = 0; i < 3; ++i) {
        int c = t + i * 256;
        xn[(size_t)r * Cc + c] = (_Float16)((vv[i] - mean) * rstd * w[c] + bia[c]);
    }
}

// ---------------- LN2 (reads fp16 x2) ----------------
__global__ __launch_bounds__(256) void ln2_kernel(
    const _Float16* __restrict__ x2, const float* __restrict__ w, const float* __restrict__ bia,
    _Float16* __restrict__ xn)
{
    int r = blockIdx.x;
    const _Float16* xr = x2 + (size_t)r * Cc;
    int t = threadIdx.x;
    float v0 = (float)xr[t], v1 = (float)xr[t + 256], v2 = (float)xr[t + 512];
    float s1 = v0 + v1 + v2;
    float s2 = v0 * v0 + v1 * v1 + v2 * v2;
    #pragma unroll
    for (int off = 32; off > 0; off >>= 1) {
        s1 += __shfl_down(s1, off);
        s2 += __shfl_down(s2, off);
    }
    __shared__ float red[8];
    int wv = t >> 6, ln = t & 63;
    if (ln == 0) { red[wv] = s1; red[4 + wv] = s2; }
    __syncthreads();
    float fs1 = red[0] + red[1] + red[2] + red[3];
    float fs2 = red[4] + red[5] + red[6] + red[7];
    float mean = fs1 * (1.0f / Cc);
    float var  = fs2 * (1.0f / Cc) - mean * mean;
    float rstd = rsqrtf(var + 1e-5f);
    float vv[3] = {v0, v1, v2};
    #pragma unroll
    for (int i = 0; i < 3; ++i) {
        int c = t + i * 256;
        xn[(size_t)r * Cc + c] = (_Float16)((vv[i] - mean) * rstd * w[c] + bia[c]);
    }
}

// ---------------- prompt mean: attP[200][10][768] -> attS rows b*Ll+l (l<10) ------
__global__ __launch_bounds__(256) void pmean_kernel(
    const _Float16* __restrict__ attP, _Float16* __restrict__ attS)
{
    int r = blockIdx.x;          // b*10 + l
    int b = r / VPT_, l = r % VPT_;
    int t = threadIdx.x;
    #pragma unroll
    for (int i = 0; i < 3; ++i) {
        int c = t + i * 256;
        float s = 0.0f;
        for (int wi = 0; wi < NWIN; ++wi)
            s += (float)attP[((size_t)((wi * Bb + b) * VPT_ + l)) * Cc + c];
        attS[((size_t)(b * Ll + l)) * Cc + c] = (_Float16)(s * (1.0f / NWIN));
    }
}

// ---------------- 256x256 / BK=64 / 8-wave MFMA fp16 GEMM ----------------
// v8: counted-vmcnt pipeline (T3/T4). Per K-tile:
//   stage(t+1) -> s_waitcnt vmcnt(8) -> s_barrier -> ds_read+MFMA -> s_barrier
// vmcnt(8) retires exactly this wave's tile-t loads (the 8 newest, tile t+1's,
// stay in flight across the barrier); first barrier makes all waves' tile-t
// writes visible; end barrier orders buf reads vs next iteration's stores.
// Last iteration drains with vmcnt(0); epilogue LDS reuse unchanged.
template <int EPI>
__global__ __launch_bounds__(512, 1) void gemm256(
    const _Float16* __restrict__ A, const _Float16* __restrict__ W,
    const float* __restrict__ bias, const _Float16* __restrict__ addsrc,
    const float* __restrict__ addF,
    _Float16* __restrict__ outH, float* __restrict__ outF,
    int M, int N, int K, int gm, int gn)
{
    __shared__ alignas(16) _Float16 AB[2][2][256 * 64];   // [buf][A/B][row*64+col]

    // supertile swizzle: groups of 8 row tiles, row-fastest inside a group
    int pid = blockIdx.x;
    int width = 8 * gn;
    int gid = pid / width;
    int first = gid * 8;
    int gsz = gm - first; if (gsz > 8) gsz = 8;
    int rem = pid - gid * width;
    int pm = first + rem % gsz;
    int pn = rem / gsz;
    int row0 = pm * 256, col0 = pn * 256;

    int tid = threadIdx.x;
    int wv = tid >> 6, ln = tid & 63;
    int n = ln & 15, quad = ln >> 4;
    int wm = wv >> 2, wn = wv & 3;          // wave tile: rows wm*128..+127, cols wn*64..+63
    int lr = ln >> 2, lg = ln & 3;

    // staging source pointers (4 issues A + 4 issues B), pre-swizzled cols
    const _Float16* gAp[4];
    const _Float16* gBp[4];
    #pragma unroll
    for (int i = 0; i < 4; ++i) {
        int slot = i * 512 + tid;
        int r = slot >> 3, p = slot & 7;
        int c = (p ^ (r & 7)) * 8;
        int ar = row0 + r; if (ar > M - 1) ar = M - 1;
        gAp[i] = A + (size_t)ar * K + c;
        gBp[i] = W + (size_t)(col0 + r) * K + c;   // N multiple of 256: no clamp
    }
    // lane frag chunk offsets (elements): logical chunk kk*4+quad, key n&7
    const int c0 = (quad ^ (n & 7)) * 8;
    const int c1 = ((4 + quad) ^ (n & 7)) * 8;

    floatx4 acc[8][4] = {};

    const int nt = K >> 6;
    int cur = 0;
    // prologue: stage tile 0 into buf 0
    #pragma unroll
    for (int i = 0; i < 4; ++i) {
        gload16(gAp[i], &AB[0][0][i * 4096 + wv * 512]);
        gload16(gBp[i], &AB[0][1][i * 4096 + wv * 512]);
    }

    for (int t = 0; t < nt; ++t) {
        if (t + 1 < nt) {                   // stage tile t+1 into the other buffer
            int k0 = (t + 1) << 6;
            #pragma unroll
            for (int i = 0; i < 4; ++i) {
                gload16(gAp[i] + k0, &AB[cur ^ 1][0][i * 4096 + wv * 512]);
                gload16(gBp[i] + k0, &AB[cur ^ 1][1][i * 4096 + wv * 512]);
            }
            asm volatile("s_waitcnt vmcnt(8)" ::: "memory");   // tile t's loads landed
        } else {
            asm volatile("s_waitcnt vmcnt(0)" ::: "memory");   // final drain
        }
        __builtin_amdgcn_sched_barrier(0);
        __builtin_amdgcn_s_barrier();       // all waves' tile-t writes visible

        const _Float16* Alds = &AB[cur][0][0] + (wm * 128 + n) * 64;
        const _Float16* Blds = &AB[cur][1][0] + (wn * 64 + n) * 64;
        half8 bf[4][2];
        #pragma unroll
        for (int j = 0; j < 4; ++j) {
            bf[j][0] = *reinterpret_cast<const half8*>(Blds + j * 1024 + c0);
            bf[j][1] = *reinterpret_cast<const half8*>(Blds + j * 1024 + c1);
        }
        #pragma unroll
        for (int i = 0; i < 8; ++i) {
            half8 a0 = *reinterpret_cast<const half8*>(Alds + i * 1024 + c0);
            half8 a1 = *reinterpret_cast<const half8*>(Alds + i * 1024 + c1);
            #pragma unroll
            for (int j = 0; j < 4; ++j) {
                acc[i][j] = __builtin_amdgcn_mfma_f32_16x16x32_f16(a0, bf[j][0], acc[i][j], 0, 0, 0);
                acc[i][j] = __builtin_amdgcn_mfma_f32_16x16x32_f16(a1, bf[j][1], acc[i][j], 0, 0, 0);
            }
        }
        asm volatile("s_waitcnt lgkmcnt(0)" ::: "memory");  // reads of buf[cur] complete
        __builtin_amdgcn_sched_barrier(0);
        __builtin_amdgcn_s_barrier();       // before next iter's stores into buf[cur]
        cur ^= 1;
    }

    float bv[4];
    #pragma unroll
    for (int j = 0; j < 4; ++j) bv[j] = bias[col0 + wn * 64 + j * 16 + n];

    if (EPI == 2) {
        #pragma unroll
        for (int i = 0; i < 8; ++i)
            #pragma unroll
            for (int j = 0; j < 4; ++j) {
                int col = col0 + wn * 64 + j * 16 + n;
                #pragma unroll
                for (int rr = 0; rr < 4; ++rr) {
                    int row = row0 + wm * 128 + i * 16 + quad * 4 + rr;
                    if (row < M) {
                        size_t off = (size_t)row * N + col;
                        outF[off] = acc[i][j][rr] + bv[j] + (float)addsrc[off];
                    }
                }
            }
    } else if (EPI == 3) {
        #pragma unroll
        for (int i = 0; i < 8; ++i)
            #pragma unroll
            for (int j = 0; j < 4; ++j) {
                int col = col0 + wn * 64 + j * 16 + n;
                #pragma unroll
                for (int rr = 0; rr < 4; ++rr) {
                    int row = row0 + wm * 128 + i * 16 + quad * 4 + rr;
                    if (row < M) {
                        size_t off = (size_t)row * N + col;
                        outH[off] = (_Float16)(acc[i][j][rr] + bv[j] + addF[off]);
                    }
                }
            }
    } else {
        // per-wave [16][72] transpose buffer carved from AB (dead after K-loop)
        _Float16* Tb = &AB[0][0][0] + wv * 1152;
        #pragma unroll
        for (int i = 0; i < 8; ++i) {
            #pragma unroll
            for (int j = 0; j < 4; ++j)
                #pragma unroll
                for (int rr = 0; rr < 4; ++rr) {
                    float v = acc[i][j][rr] + bv[j];
                    if (EPI == 1) v = 0.5f * v * (1.0f + erff(v * 0.70710678118654752f));
                    Tb[(quad * 4 + rr) * 72 + j * 16 + n] = (_Float16)v;
                }
            __syncthreads();   // lockstep; guarantees write->read ordering
            int row = row0 + wm * 128 + i * 16 + lr;
            if (row < M) {
                uint4 p0 = *reinterpret_cast<const uint4*>(&Tb[lr * 72 + lg * 8]);
                uint4 p1 = *reinterpret_cast<const uint4*>(&Tb[lr * 72 + 32 + lg * 8]);
                _Float16* po = outH + (size_t)row * N + col0 + wn * 64 + lg * 8;
                *reinterpret_cast<uint4*>(po) = p0;
                *reinterpret_cast<uint4*>(po + 32) = p1;
            }
        }
    }
}

// ---------------- MFMA attention: one block per (window, head), 4 waves ----------------
// v8 = v7 minus s_setprio (neutral-to-negative in v7 A/B); vectorized V staging kept.
__global__ __launch_bounds__(256, 2) void attn_mfma_kernel(
    const _Float16* __restrict__ qkv, const _Float16* __restrict__ qkvbh,
    const float* __restrict__ relh, const float* __restrict__ relw,
    _Float16* __restrict__ attS, _Float16* __restrict__ attP)
{
    __shared__ alignas(16) _Float16 Ks[208 * 72];
    __shared__ alignas(16) _Float16 Vt[64 * 232];
    __shared__ alignas(16) _Float16 Pc[4][16 * 40];
    __shared__ alignas(16) float    Tabs[4][896];   // per-wave: tw[16][28], th[16][28]
    __shared__ int rowOff[208];
    const int bwi = blockIdx.x / NHh, hh = blockIdx.x % NHh;
    const int tid = threadIdx.x;

    const int bp = bwi & 7;            // prompt batch (block = wi*8 + b)
    const int bs = bwi / NWIN;         // spatial batch (block = b*25 + wi)
    const int wis = bwi % NWIN;
    const int wh = wis / 5, ww = wis % 5;

    const int wv = tid >> 6, ln = tid & 63;
    const int n = ln & 15, quad = ln >> 4;

    // ---- row -> global-row table (reference concat pairing; -1 = bias/pad row) ----
    if (tid < 208) {
        int row = tid, off = -1;
        if (row < VPT_) off = bp * Ll + row;
        else if (row < LW_) {
            int s = row - VPT_;
            int i = s / WSz, j = s - i * WSz;
            int gi = wh * WSz + i, gj = ww * WSz + j;
            if (gi < 64 && gj < 64) off = bs * Ll + VPT_ + gi * 64 + gj;
        }
        rowOff[row] = off;
    }

    // ---- rel tables -> registers (B operands for rel MFMAs) ----
    half8 bh[2][2], bwf[2][2];
    #pragma unroll
    for (int ct = 0; ct < 2; ++ct) {
        int j = ct * 16 + n; if (j > 26) j = 26;
        #pragma unroll
        for (int kk = 0; kk < 2; ++kk) {
            const float* ph = relh + j * 64 + kk * 32 + quad * 8;
            const float* pw = relw + j * 64 + kk * 32 + quad * 8;
            half8 hf, wf;
            #pragma unroll
            for (int e = 0; e < 8; ++e) { hf[e] = (_Float16)ph[e]; wf[e] = (_Float16)pw[e]; }
            bh[ct][kk] = hf; bwf[ct][kk] = wf;
        }
    }

    int khv[13], kwv[13];
    #pragma unroll
    for (int ct = 0; ct < 13; ++ct) {
        int key = ct * 16 + n;
        int k2 = key - VPT_; if (k2 < 0) k2 = 0;
        khv[ct] = k2 / WSz; kwv[ct] = k2 - khv[ct] * WSz;
    }
    __syncthreads();   // rowOff ready

    // ---- initial Q load for rt = wv ----
    half8 qa0, qa1;
    {
        int qrow = wv * 16 + n; if (qrow > 205) qrow = 205;
        int ro = rowOff[qrow];
        const _Float16* qp = (ro >= 0 ? qkv + (size_t)ro * 2304 : qkvbh) + hh * HDd + quad * 8;
        qa0 = *reinterpret_cast<const half8*>(qp);
        qa1 = *reinterpret_cast<const half8*>(qp + 32);
    }

    // ---- stage K: rows 0..205 (rows 206/207 masked later) ----
    for (int idx = tid; idx < LW_ * 8; idx += 256) {
        int row = idx >> 3, c8 = idx & 7;
        int ro = rowOff[row];
        const _Float16* src = (ro >= 0 ? qkv + (size_t)ro * 2304 : qkvbh) + 768 + hh * HDd;
        *reinterpret_cast<uint4*>(&Ks[row * 72 + c8 * 8]) =
            *reinterpret_cast<const uint4*>(src + c8 * 8);
    }
    // ---- stage V column-major: 8-row blocks, one b128 write per task ----
    for (int task = tid; task < 26 * 64; task += 256) {
        int d = task & 63, rb = task >> 6;       // keys rb*8 .. rb*8+7
        half8 v;
        #pragma unroll
        for (int rrr = 0; rrr < 8; ++rrr) {
            int row = rb * 8 + rrr;
            _Float16 val = (_Float16)0.0f;
            if (row < LW_) {
                int ro = rowOff[row];
                const _Float16* src = (ro >= 0 ? qkv + (size_t)ro * 2304 : qkvbh) + 1536 + hh * HDd;
                val = src[d];
            }
            v[rrr] = val;
        }
        *reinterpret_cast<half8*>(&Vt[d * 232 + rb * 8]) = v;
    }
    // zero-fill key-columns 208..223 (read by PV kt=6), b128
    for (int task = tid; task < 64 * 2; task += 256) {
        int d = task >> 1, c = task & 1;
        *reinterpret_cast<half8*>(&Vt[d * 232 + 208 + c * 8]) = half8{};
    }
    __syncthreads();

    float* tw_t = Tabs[wv];            // [16][28]
    float* th_t = Tabs[wv] + 448;      // [16][28]
    _Float16* pcw = &Pc[wv][0];

    for (int rt = wv; rt < 13; rt += 4) {
        // prefetch next tile's Q (consumed next iteration)
        int nrt = rt + 4; if (nrt > 12) nrt = 12;
        int nqrow = nrt * 16 + n; if (nqrow > 205) nqrow = 205;
        int nro = rowOff[nqrow];
        const _Float16* nqp = (nro >= 0 ? qkv + (size_t)nro * 2304 : qkvbh) + hh * HDd + quad * 8;
        half8 nq0 = *reinterpret_cast<const half8*>(nqp);
        half8 nq1 = *reinterpret_cast<const half8*>(nqp + 32);

        // rel-pos projections th = q@Rh^T, tw = q@Rw^T  (cols j = 0..26)
        floatx4 th0 = {}, th1 = {}, tw0 = {}, tw1 = {};
        th0 = __builtin_amdgcn_mfma_f32_16x16x32_f16(qa0, bh[0][0], th0, 0, 0, 0);
        th0 = __builtin_amdgcn_mfma_f32_16x16x32_f16(qa1, bh[0][1], th0, 0, 0, 0);
        th1 = __builtin_amdgcn_mfma_f32_16x16x32_f16(qa0, bh[1][0], th1, 0, 0, 0);
        th1 = __builtin_amdgcn_mfma_f32_16x16x32_f16(qa1, bh[1][1], th1, 0, 0, 0);
        tw0 = __builtin_amdgcn_mfma_f32_16x16x32_f16(qa0, bwf[0][0], tw0, 0, 0, 0);
        tw0 = __builtin_amdgcn_mfma_f32_16x16x32_f16(qa1, bwf[0][1], tw0, 0, 0, 0);
        tw1 = __builtin_amdgcn_mfma_f32_16x16x32_f16(qa0, bwf[1][0], tw1, 0, 0, 0);
        tw1 = __builtin_amdgcn_mfma_f32_16x16x32_f16(qa1, bwf[1][1], tw1, 0, 0, 0);

        // write per-wave gather tables: T[lrow][j]; cols 0..15 from *0, 16..27 from *1
        #pragma unroll
        for (int rr = 0; rr < 4; ++rr) {
            int lrow = quad * 4 + rr;
            th_t[lrow * 28 + n] = th0[rr];
            tw_t[lrow * 28 + n] = tw0[rr];
            if (n < 12) {
                th_t[lrow * 28 + 16 + n] = th1[rr];
                tw_t[lrow * 28 + 16 + n] = tw1[rr];
            }
        }

        // QK^T
        floatx4 s[13];
        #pragma unroll
        for (int ct = 0; ct < 13; ++ct) {
            half8 kb0 = *reinterpret_cast<const half8*>(&Ks[(ct * 16 + n) * 72 + quad * 8]);
            half8 kb1 = *reinterpret_cast<const half8*>(&Ks[(ct * 16 + n) * 72 + 32 + quad * 8]);
            floatx4 a = {};
            a = __builtin_amdgcn_mfma_f32_16x16x32_f16(qa0, kb0, a, 0, 0, 0);
            a = __builtin_amdgcn_mfma_f32_16x16x32_f16(qa1, kb1, a, 0, 0, 0);
            s[ct] = a;
        }

        // scale + rel bias (LDS table gather) + masking
        #pragma unroll
        for (int rr = 0; rr < 4; ++rr) {
            int row = rt * 16 + quad * 4 + rr;
            bool rowok = (row >= VPT_) && (row < LW_);
            int q2 = row - VPT_; if (q2 < 0) q2 = 0;
            int qh = q2 / WSz, qw = q2 - qh * WSz;
            const float* thr = th_t + (quad * 4 + rr) * 28;
            const float* twr = tw_t + (quad * 4 + rr) * 28;
            #pragma unroll
            for (int ct = 0; ct < 13; ++ct) {
                int key = ct * 16 + n;
                float tv = thr[qh - khv[ct] + 13] + twr[qw - kwv[ct] + 13];
                float sv = s[ct][rr] * 0.125f;
                sv += (rowok && key >= VPT_ && key < LW_) ? tv : 0.0f;
                if (key >= LW_) sv = -1e30f;
                s[ct][rr] = sv;
            }
        }

        // softmax over keys (lanes n within 16-group hold key tiles)
        float mx[4] = {-1e30f, -1e30f, -1e30f, -1e30f};
        #pragma unroll
        for (int ct = 0; ct < 13; ++ct)
            #pragma unroll
            for (int rr = 0; rr < 4; ++rr) mx[rr] = fmaxf(mx[rr], s[ct][rr]);
        #pragma unroll
        for (int rr = 0; rr < 4; ++rr)
            #pragma unroll
            for (int off = 1; off < 16; off <<= 1) mx[rr] = fmaxf(mx[rr], __shfl_xor(mx[rr], off));
        float sm[4] = {0.f, 0.f, 0.f, 0.f};
        #pragma unroll
        for (int ct = 0; ct < 13; ++ct)
            #pragma unroll
            for (int rr = 0; rr < 4; ++rr) {
                float p = __expf(s[ct][rr] - mx[rr]);
                s[ct][rr] = p; sm[rr] += p;
            }
        #pragma unroll
        for (int rr = 0; rr < 4; ++rr) {
            #pragma unroll
            for (int off = 1; off < 16; off <<= 1) sm[rr] += __shfl_xor(sm[rr], off);
            sm[rr] = 1.0f / sm[rr];
        }
        #pragma unroll
        for (int ct = 0; ct < 13; ++ct)
            #pragma unroll
            for (int rr = 0; rr < 4; ++rr) s[ct][rr] *= sm[rr];

        // PV: per 32-key block, one K=32 MFMA per d-tile (proven path)
        floatx4 o[4] = {};
        #pragma unroll
        for (int kt = 0; kt < 7; ++kt) {
            #pragma unroll
            for (int h2 = 0; h2 < 2; ++h2) {
                int ct = kt * 2 + h2;
                #pragma unroll
                for (int rr = 0; rr < 4; ++rr) {
                    float pv = (ct < 13) ? s[ct][rr] : 0.0f;
                    pcw[(quad * 4 + rr) * 40 + h2 * 16 + n] = (_Float16)pv;
                }
            }
            half8 pa = *reinterpret_cast<const half8*>(&pcw[n * 40 + quad * 8]);
            #pragma unroll
            for (int dt = 0; dt < 4; ++dt) {
                half8 vb = *reinterpret_cast<const half8*>(&Vt[(dt * 16 + n) * 232 + kt * 32 + quad * 8]);
                o[dt] = __builtin_amdgcn_mfma_f32_16x16x32_f16(pa, vb, o[dt], 0, 0, 0);
            }
        }

        // scatter stores: prompt rows -> attP, in-range spatial rows -> attS
        #pragma unroll
        for (int dt = 0; dt < 4; ++dt)
            #pragma unroll
            for (int rr = 0; rr < 4; ++rr) {
                int row = rt * 16 + quad * 4 + rr;
                if (row >= LW_) continue;
                _Float16 val = (_Float16)o[dt][rr];
                int col = hh * HDd + dt * 16 + n;
                if (row < VPT_) {
                    attP[((size_t)(bwi * VPT_ + row)) * Cc + col] = val;
                } else {
                    int g = rowOff[row];
                    if (g >= 0) attS[(size_t)g * Cc + col] = val;
                }
            }

        qa0 = nq0; qa1 = nq1;
    }
}

// ---------------- launcher ----------------
extern "C" void kernel_launch(void* const* d_in, const int* in_sizes, int n_in,
                              void* d_out, int out_size, void* d_ws, size_t ws_size,
                              hipStream_t stream)
{
    const float* x     = (const float*)d_in[0];
    const float* ln1w  = (const float*)d_in[1];
    const float* ln1b  = (const float*)d_in[2];
    const float* qkvw  = (const float*)d_in[3];
    const float* qkvb  = (const float*)d_in[4];
    const float* projw = (const float*)d_in[5];
    const float* projb = (const float*)d_in[6];
    const float* relh  = (const float*)d_in[7];
    const float* relw  = (const float*)d_in[8];
    const float* ln2w  = (const float*)d_in[9];
    const float* ln2b  = (const float*)d_in[10];
    const float* w1    = (const float*)d_in[11];
    const float* b1    = (const float*)d_in[12];
    const float* w2    = (const float*)d_in[13];
    const float* b2    = (const float*)d_in[14];
    float* out = (float*)d_out;
    char* ws = (char*)d_ws;

    // workspace layout (bytes); peak 228.8 MB (during QKV gemm)
    _Float16* wqkv_h  = (_Float16*)(ws + 0);          // 2304*768*2   = 3,538,944
    _Float16* wproj_h = (_Float16*)(ws + 3538944);    //  768*768*2   = 1,179,648
    _Float16* w1_h    = (_Float16*)(ws + 4718592);    // 3072*768*2   = 4,718,592
    _Float16* w2_h    = (_Float16*)(ws + 9437184);    //  768*3072*2  = 4,718,592
    _Float16* qkvb_h  = (_Float16*)(ws + 14155776);   // 2304*2       = 4,608
    _Float16* attP    = (_Float16*)(ws + 14160384);   // 200*10*768*2 = 3,072,000
    _Float16* tokA    = (_Float16*)(ws + 17232384);   // region A: 32848*768*2 = 50,454,528
    char* regB = ws + 77438976;
    _Float16* qkv_h  = (_Float16*)regB;               // 32848*2304*2 = 151,363,584 (dies after attn)
    _Float16* hbuf   = (_Float16*)regB;               // 16424*3072*2 = 100,909,056 (MLP phase)
    _Float16* x2h    = (_Float16*)(regB + 100909056); // 32848*768*2  = 50,454,528

    // 1. weights + qkv bias -> fp16
    f2h_kernel<<<(2304 * 768 + 255) / 256, 256, 0, stream>>>(qkvw, wqkv_h, 2304 * 768);
    f2h_kernel<<<(768 * 768 + 255) / 256, 256, 0, stream>>>(projw, wproj_h, 768 * 768);
    f2h_kernel<<<(3072 * 768 + 255) / 256, 256, 0, stream>>>(w1, w1_h, 3072 * 768);
    f2h_kernel<<<(768 * 3072 + 255) / 256, 256, 0, stream>>>(w2, w2_h, 768 * 3072);
    f2h_kernel<<<9, 256, 0, stream>>>(qkvb, qkvb_h, 2304);
    // 2. LN1 (contiguous; no window scatter, no memset)
    ln1_kernel<<<Bb * Ll, 256, 0, stream>>>(x, ln1w, ln1b, tokA);
    // 3. QKV gemm on distinct rows only (M=32848, N=2304, K=768), grid 129x9
    gemm256<0><<<129 * 9, 512, 0, stream>>>(tokA, wqkv_h, qkvb, nullptr, nullptr, qkv_h, nullptr,
                                            32848, 2304, 768, 129, 9);
    // 4. MFMA attention (gathers windows via rowOff) -> attS (region A) + attP
    attn_mfma_kernel<<<BW_ * NHh, 256, 0, stream>>>(qkv_h, qkvb_h, relh, relw, tokA, attP);
    // 5. prompt mean over 25 windows -> attS rows l<10
    pmean_kernel<<<Bb * VPT_, 256, 0, stream>>>(attP, tokA);
    // 6. proj gemm (M=32848) fused with x2 = x + proj + bias (EPI 3) -> x2h fp16
    gemm256<3><<<129 * 3, 512, 0, stream>>>(tokA, wproj_h, projb, nullptr, x, x2h, nullptr,
                                            32848, 768, 768, 129, 3);
    // 7. LN2 -> xn2 (region A)
    ln2_kernel<<<Bb * Ll, 256, 0, stream>>>(x2h, ln2w, ln2b, tokA);
    // 8. MLP in 2 chunks of 16424 rows (hbuf reuses regB head; qkv dead by now)
    for (int ch = 0; ch < 2; ++ch) {
        size_t r0 = (size_t)ch * 16424;
        gemm256<1><<<65 * 12, 512, 0, stream>>>(tokA + r0 * 768, w1_h, b1, nullptr, nullptr, hbuf, nullptr,
                                                16424, 3072, 768, 65, 12);
        gemm256<2><<<65 * 3, 512, 0, stream>>>(hbuf, w2_h, b2, x2h + r0 * 768, nullptr, nullptr, out + r0 * 768,
                                               16424, 768, 3072, 65, 3);
    }
}

// Round 9
// 1187.148 us; speedup vs baseline: 1.0787x; 1.0787x over previous
//
#include <hip/hip_runtime.h>
#include <hip/hip_fp16.h>

// ---- problem constants ----
#define Bb 8
#define Ll 4106
#define Cc 768
#define VPT_ 10
#define WSz 14
#define NWIN 25
#define BW_ 200
#define LW_ 206
#define NHh 12
#define HDd 64

typedef _Float16 half8 __attribute__((ext_vector_type(8)));
typedef float floatx4 __attribute__((ext_vector_type(4)));

// async global->LDS, 16 B per lane, wave-uniform LDS base + lane*16
__device__ __forceinline__ void gload16(const _Float16* g, _Float16* l) {
    __builtin_amdgcn_global_load_lds(
        (const __attribute__((address_space(1))) void*)g,
        (__attribute__((address_space(3))) void*)l, 16, 0, 0);
}

// ---------------- fp32 -> fp16 convert (all 5 weight arrays in one launch) ---------
__global__ void f2h_all_kernel(
    const float* __restrict__ a, _Float16* __restrict__ oa, int na,
    const float* __restrict__ b, _Float16* __restrict__ ob, int nb,
    const float* __restrict__ c, _Float16* __restrict__ oc, int nc,
    const float* __restrict__ d, _Float16* __restrict__ od, int nd,
    const float* __restrict__ e, _Float16* __restrict__ oe, int ne)
{
    int i = blockIdx.x * 256 + threadIdx.x;
    if (i < na) { oa[i] = (_Float16)a[i]; return; }
    i -= na;
    if (i < nb) { ob[i] = (_Float16)b[i]; return; }
    i -= nb;
    if (i < nc) { oc[i] = (_Float16)c[i]; return; }
    i -= nc;
    if (i < nd) { od[i] = (_Float16)d[i]; return; }
    i -= nd;
    if (i < ne) { oe[i] = (_Float16)e[i]; }
}

// ---------------- LN1 (contiguous rows, no scatter) ----------------
__global__ __launch_bounds__(256) void ln1_kernel(
    const float* __restrict__ x, const float* __restrict__ w, const float* __restrict__ bia,
    _Float16* __restrict__ xn)
{
    int r = blockIdx.x;
    const float* xr = x + (size_t)r * Cc;
    int t = threadIdx.x;
    float v0 = xr[t], v1 = xr[t + 256], v2 = xr[t + 512];
    float s1 = v0 + v1 + v2;
    float s2 = v0 * v0 + v1 * v1 + v2 * v2;
    #pragma unroll
    for (int off = 32; off > 0; off >>= 1) {
        s1 += __shfl_down(s1, off);
        s2 += __shfl_down(s2, off);
    }
    __shared__ float red[8];
    int wv = t >> 6, ln = t & 63;
    if (ln == 0) { red[wv] = s1; red[4 + wv] = s2; }
    __syncthreads();
    float fs1 = red[0] + red[1] + red[2] + red[3];
    float fs2 = red[4] + red[5] + red[6] + red[7];
    float mean = fs1 * (1.0f / Cc);
    float var  = fs2 * (1.0f / Cc) - mean * mean;
    float rstd = rsqrtf(var + 1e-5f);
    float vv[3] = {v0, v1, v2};
    #pragma unroll
    for (int i = 0; i < 3; ++i) {
        int c = t + i * 256;
        xn[(size_t)r * Cc + c] = (_Float16)((vv[i] - mean) * rstd * w[c] + bia[c]);
    }
}

// ---------------- LN2 (reads fp16 x2) ----------------
__global__ __launch_bounds__(256) void ln2_kernel(
    const _Float16* __restrict__ x2, const float* __restrict__ w, const float* __restrict__ bia,
    _Float16* __restrict__ xn)
{
    int r = blockIdx.x;
    const _Float16* xr = x2 + (size_t)r * Cc;
    int t = threadIdx.x;
    float v0 = (float)xr[t], v1 = (float)xr[t + 256], v2 = (float)xr[t + 512];
    float s1 = v0 + v1 + v2;
    float s2 = v0 * v0 + v1 * v1 + v2 * v2;
    #pragma unroll
    for (int off = 32; off > 0; off >>= 1) {
        s1 += __shfl_down(s1, off);
        s2 += __shfl_down(s2, off);
    }
    __shared__ float red[8];
    int wv = t >> 6, ln = t & 63;
    if (ln == 0) { red[wv] = s1; red[4 + wv] = s2; }
    __syncthreads();
    float fs1 = red[0] + red[1] + red[2] + red[3];
    float fs2 = red[4] + red[5] + red[6] + red[7];
    float mean = fs1 * (1.0f / Cc);
    float var  = fs2 * (1.0f / Cc) - mean * mean;
    float rstd = rsqrtf(var + 1e-5f);
    float vv[3] = {v0, v1, v2};
    #pragma unroll
    for (int i = 0; i < 3; ++i) {
        int c = t + i * 256;
        xn[(size_t)r * Cc + c] = (_Float16)((vv[i] - mean) * rstd * w[c] + bia[c]);
    }
}

// ---------------- prompt mean: attP[200][10][768] -> attS rows b*Ll+l (l<10) ------
__global__ __launch_bounds__(256) void pmean_kernel(
    const _Float16* __restrict__ attP, _Float16* __restrict__ attS)
{
    int r = blockIdx.x;          // b*10 + l
    int b = r / VPT_, l = r % VPT_;
    int t = threadIdx.x;
    #pragma unroll
    for (int i = 0; i < 3; ++i) {
        int c = t + i * 256;
        float s = 0.0f;
        for (int wi = 0; wi < NWIN; ++wi)
            s += (float)attP[((size_t)((wi * Bb + b) * VPT_ + l)) * Cc + c];
        attS[((size_t)(b * Ll + l)) * Cc + c] = (_Float16)(s * (1.0f / NWIN));
    }
}

// ---------------- 256x256 / BK=64 / 8-wave MFMA fp16 GEMM ----------------
// v9 = revert to the PROVEN v6 sync structure (single __syncthreads per K-tile;
// v8's counted-vmcnt + double-barrier regressed: extra barrier + sched pinning
// cost more than the drain it saved — loads have the full MFMA phase to land).
template <int EPI>
__global__ __launch_bounds__(512, 1) void gemm256(
    const _Float16* __restrict__ A, const _Float16* __restrict__ W,
    const float* __restrict__ bias, const _Float16* __restrict__ addsrc,
    const float* __restrict__ addF,
    _Float16* __restrict__ outH, float* __restrict__ outF,
    int M, int N, int K, int gm, int gn)
{
    __shared__ alignas(16) _Float16 AB[2][2][256 * 64];   // [buf][A/B][row*64+col]

    // supertile swizzle: groups of 8 row tiles, row-fastest inside a group
    int pid = blockIdx.x;
    int width = 8 * gn;
    int gid = pid / width;
    int first = gid * 8;
    int gsz = gm - first; if (gsz > 8) gsz = 8;
    int rem = pid - gid * width;
    int pm = first + rem % gsz;
    int pn = rem / gsz;
    int row0 = pm * 256, col0 = pn * 256;

    int tid = threadIdx.x;
    int wv = tid >> 6, ln = tid & 63;
    int n = ln & 15, quad = ln >> 4;
    int wm = wv >> 2, wn = wv & 3;          // wave tile: rows wm*128..+127, cols wn*64..+63
    int lr = ln >> 2, lg = ln & 3;

    // staging source pointers (4 issues A + 4 issues B), pre-swizzled cols
    const _Float16* gAp[4];
    const _Float16* gBp[4];
    #pragma unroll
    for (int i = 0; i < 4; ++i) {
        int slot = i * 512 + tid;
        int r = slot >> 3, p = slot & 7;
        int c = (p ^ (r & 7)) * 8;
        int ar = row0 + r; if (ar > M - 1) ar = M - 1;
        gAp[i] = A + (size_t)ar * K + c;
        gBp[i] = W + (size_t)(col0 + r) * K + c;   // N multiple of 256: no clamp
    }
    // lane frag chunk offsets (elements): logical chunk kk*4+quad, key n&7
    const int c0 = (quad ^ (n & 7)) * 8;
    const int c1 = ((4 + quad) ^ (n & 7)) * 8;

    floatx4 acc[8][4] = {};

    const int nt = K >> 6;
    int cur = 0;
    // prologue: stage tile 0 into buf 0
    #pragma unroll
    for (int i = 0; i < 4; ++i) {
        gload16(gAp[i], &AB[0][0][i * 4096 + wv * 512]);
        gload16(gBp[i], &AB[0][1][i * 4096 + wv * 512]);
    }
    __syncthreads();                        // drains vmcnt: tile 0 visible

    for (int t = 0; t < nt; ++t) {
        if (t + 1 < nt) {                   // stage tile t+1 into the other buffer
            int k0 = (t + 1) << 6;
            #pragma unroll
            for (int i = 0; i < 4; ++i) {
                gload16(gAp[i] + k0, &AB[cur ^ 1][0][i * 4096 + wv * 512]);
                gload16(gBp[i] + k0, &AB[cur ^ 1][1][i * 4096 + wv * 512]);
            }
        }
        const _Float16* Alds = &AB[cur][0][0] + (wm * 128 + n) * 64;
        const _Float16* Blds = &AB[cur][1][0] + (wn * 64 + n) * 64;
        half8 bf[4][2];
        #pragma unroll
        for (int j = 0; j < 4; ++j) {
            bf[j][0] = *reinterpret_cast<const half8*>(Blds + j * 1024 + c0);
            bf[j][1] = *reinterpret_cast<const half8*>(Blds + j * 1024 + c1);
        }
        #pragma unroll
        for (int i = 0; i < 8; ++i) {
            half8 a0 = *reinterpret_cast<const half8*>(Alds + i * 1024 + c0);
            half8 a1 = *reinterpret_cast<const half8*>(Alds + i * 1024 + c1);
            #pragma unroll
            for (int j = 0; j < 4; ++j) {
                acc[i][j] = __builtin_amdgcn_mfma_f32_16x16x32_f16(a0, bf[j][0], acc[i][j], 0, 0, 0);
                acc[i][j] = __builtin_amdgcn_mfma_f32_16x16x32_f16(a1, bf[j][1], acc[i][j], 0, 0, 0);
            }
        }
        __syncthreads();   // all reads of buf[cur] done; staged tile t+1 visible
        cur ^= 1;
    }

    float bv[4];
    #pragma unroll
    for (int j = 0; j < 4; ++j) bv[j] = bias[col0 + wn * 64 + j * 16 + n];

    if (EPI == 2) {
        #pragma unroll
        for (int i = 0; i < 8; ++i)
            #pragma unroll
            for (int j = 0; j < 4; ++j) {
                int col = col0 + wn * 64 + j * 16 + n;
                #pragma unroll
                for (int rr = 0; rr < 4; ++rr) {
                    int row = row0 + wm * 128 + i * 16 + quad * 4 + rr;
                    if (row < M) {
                        size_t off = (size_t)row * N + col;
                        outF[off] = acc[i][j][rr] + bv[j] + (float)addsrc[off];
                    }
                }
            }
    } else if (EPI == 3) {
        #pragma unroll
        for (int i = 0; i < 8; ++i)
            #pragma unroll
            for (int j = 0; j < 4; ++j) {
                int col = col0 + wn * 64 + j * 16 + n;
                #pragma unroll
                for (int rr = 0; rr < 4; ++rr) {
                    int row = row0 + wm * 128 + i * 16 + quad * 4 + rr;
                    if (row < M) {
                        size_t off = (size_t)row * N + col;
                        outH[off] = (_Float16)(acc[i][j][rr] + bv[j] + addF[off]);
                    }
                }
            }
    } else {
        // per-wave [16][72] transpose buffer carved from AB (dead after K-loop)
        _Float16* Tb = &AB[0][0][0] + wv * 1152;
        #pragma unroll
        for (int i = 0; i < 8; ++i) {
            #pragma unroll
            for (int j = 0; j < 4; ++j)
                #pragma unroll
                for (int rr = 0; rr < 4; ++rr) {
                    float v = acc[i][j][rr] + bv[j];
                    if (EPI == 1) v = 0.5f * v * (1.0f + erff(v * 0.70710678118654752f));
                    Tb[(quad * 4 + rr) * 72 + j * 16 + n] = (_Float16)v;
                }
            __syncthreads();   // lockstep; guarantees write->read ordering
            int row = row0 + wm * 128 + i * 16 + lr;
            if (row < M) {
                uint4 p0 = *reinterpret_cast<const uint4*>(&Tb[lr * 72 + lg * 8]);
                uint4 p1 = *reinterpret_cast<const uint4*>(&Tb[lr * 72 + 32 + lg * 8]);
                _Float16* po = outH + (size_t)row * N + col0 + wn * 64 + lg * 8;
                *reinterpret_cast<uint4*>(po) = p0;
                *reinterpret_cast<uint4*>(po + 32) = p1;
            }
        }
    }
}

// ---------------- MFMA attention: one block per (window, head), 4 waves ----------------
// v9: VALU-trimmed scale/bias gather (the kernel is VALU-issue-bound):
//  - row-validity folded into the table WRITES (invalid rows store 0) — 16 selects
//    per tile instead of 52 select-chains in the gather loop.
//  - per-wave offset arrays oh/ow = 13 - khv/kwv; inner body for ct=1..11 is
//    s = s*0.125 + (pth[oh]+ptw[ow])  (exact same f32 rounding order as before).
//  - ct=0 keeps the key<VPT select; ct=12 keeps the -1e30 overwrite (n>=14).
//    tw table precedes th so ct=12's discarded pth[-1] read stays in-bounds.
__global__ __launch_bounds__(256, 2) void attn_mfma_kernel(
    const _Float16* __restrict__ qkv, const _Float16* __restrict__ qkvbh,
    const float* __restrict__ relh, const float* __restrict__ relw,
    _Float16* __restrict__ attS, _Float16* __restrict__ attP)
{
    __shared__ alignas(16) _Float16 Ks[208 * 72];
    __shared__ alignas(16) _Float16 Vt[64 * 232];
    __shared__ alignas(16) _Float16 Pc[4][16 * 40];
    __shared__ alignas(16) float    Tabs[4][896];   // per-wave: tw[16][28], th[16][28]
    __shared__ int rowOff[208];
    const int bwi = blockIdx.x / NHh, hh = blockIdx.x % NHh;
    const int tid = threadIdx.x;

    const int bp = bwi & 7;            // prompt batch (block = wi*8 + b)
    const int bs = bwi / NWIN;         // spatial batch (block = b*25 + wi)
    const int wis = bwi % NWIN;
    const int wh = wis / 5, ww = wis % 5;

    const int wv = tid >> 6, ln = tid & 63;
    const int n = ln & 15, quad = ln >> 4;

    // ---- row -> global-row table (reference concat pairing; -1 = bias/pad row) ----
    if (tid < 208) {
        int row = tid, off = -1;
        if (row < VPT_) off = bp * Ll + row;
        else if (row < LW_) {
            int s = row - VPT_;
            int i = s / WSz, j = s - i * WSz;
            int gi = wh * WSz + i, gj = ww * WSz + j;
            if (gi < 64 && gj < 64) off = bs * Ll + VPT_ + gi * 64 + gj;
        }
        rowOff[row] = off;
    }

    // ---- rel tables -> registers (B operands for rel MFMAs) ----
    half8 bh[2][2], bwf[2][2];
    #pragma unroll
    for (int ct = 0; ct < 2; ++ct) {
        int j = ct * 16 + n; if (j > 26) j = 26;
        #pragma unroll
        for (int kk = 0; kk < 2; ++kk) {
            const float* ph = relh + j * 64 + kk * 32 + quad * 8;
            const float* pw = relw + j * 64 + kk * 32 + quad * 8;
            half8 hf, wf;
            #pragma unroll
            for (int e = 0; e < 8; ++e) { hf[e] = (_Float16)ph[e]; wf[e] = (_Float16)pw[e]; }
            bh[ct][kk] = hf; bwf[ct][kk] = wf;
        }
    }

    int oh[13], ow[13];
    #pragma unroll
    for (int ct = 0; ct < 13; ++ct) {
        int key = ct * 16 + n;
        int k2 = key - VPT_; if (k2 < 0) k2 = 0;
        int kh = k2 / WSz;
        oh[ct] = 13 - kh;
        ow[ct] = 13 - (k2 - kh * WSz);
    }
    __syncthreads();   // rowOff ready

    // ---- initial Q load for rt = wv ----
    half8 qa0, qa1;
    {
        int qrow = wv * 16 + n; if (qrow > 205) qrow = 205;
        int ro = rowOff[qrow];
        const _Float16* qp = (ro >= 0 ? qkv + (size_t)ro * 2304 : qkvbh) + hh * HDd + quad * 8;
        qa0 = *reinterpret_cast<const half8*>(qp);
        qa1 = *reinterpret_cast<const half8*>(qp + 32);
    }

    // ---- stage K: rows 0..205 (rows 206/207 masked later) ----
    for (int idx = tid; idx < LW_ * 8; idx += 256) {
        int row = idx >> 3, c8 = idx & 7;
        int ro = rowOff[row];
        const _Float16* src = (ro >= 0 ? qkv + (size_t)ro * 2304 : qkvbh) + 768 + hh * HDd;
        *reinterpret_cast<uint4*>(&Ks[row * 72 + c8 * 8]) =
            *reinterpret_cast<const uint4*>(src + c8 * 8);
    }
    // ---- stage V column-major: 8-row blocks, one b128 write per task ----
    for (int task = tid; task < 26 * 64; task += 256) {
        int d = task & 63, rb = task >> 6;       // keys rb*8 .. rb*8+7
        half8 v;
        #pragma unroll
        for (int rrr = 0; rrr < 8; ++rrr) {
            int row = rb * 8 + rrr;
            _Float16 val = (_Float16)0.0f;
            if (row < LW_) {
                int ro = rowOff[row];
                const _Float16* src = (ro >= 0 ? qkv + (size_t)ro * 2304 : qkvbh) + 1536 + hh * HDd;
                val = src[d];
            }
            v[rrr] = val;
        }
        *reinterpret_cast<half8*>(&Vt[d * 232 + rb * 8]) = v;
    }
    // zero-fill key-columns 208..223 (read by PV kt=6), b128
    for (int task = tid; task < 64 * 2; task += 256) {
        int d = task >> 1, c = task & 1;
        *reinterpret_cast<half8*>(&Vt[d * 232 + 208 + c * 8]) = half8{};
    }
    __syncthreads();

    float* tw_t = Tabs[wv];            // [16][28]
    float* th_t = Tabs[wv] + 448;      // [16][28]
    _Float16* pcw = &Pc[wv][0];

    for (int rt = wv; rt < 13; rt += 4) {
        // prefetch next tile's Q (consumed next iteration)
        int nrt = rt + 4; if (nrt > 12) nrt = 12;
        int nqrow = nrt * 16 + n; if (nqrow > 205) nqrow = 205;
        int nro = rowOff[nqrow];
        const _Float16* nqp = (nro >= 0 ? qkv + (size_t)nro * 2304 : qkvbh) + hh * HDd + quad * 8;
        half8 nq0 = *reinterpret_cast<const half8*>(nqp);
        half8 nq1 = *reinterpret_cast<const half8*>(nqp + 32);

        // rel-pos projections th = q@Rh^T, tw = q@Rw^T  (cols j = 0..26)
        floatx4 th0 = {}, th1 = {}, tw0 = {}, tw1 = {};
        th0 = __builtin_amdgcn_mfma_f32_16x16x32_f16(qa0, bh[0][0], th0, 0, 0, 0);
        th0 = __builtin_amdgcn_mfma_f32_16x16x32_f16(qa1, bh[0][1], th0, 0, 0, 0);
        th1 = __builtin_amdgcn_mfma_f32_16x16x32_f16(qa0, bh[1][0], th1, 0, 0, 0);
        th1 = __builtin_amdgcn_mfma_f32_16x16x32_f16(qa1, bh[1][1], th1, 0, 0, 0);
        tw0 = __builtin_amdgcn_mfma_f32_16x16x32_f16(qa0, bwf[0][0], tw0, 0, 0, 0);
        tw0 = __builtin_amdgcn_mfma_f32_16x16x32_f16(qa1, bwf[0][1], tw0, 0, 0, 0);
        tw1 = __builtin_amdgcn_mfma_f32_16x16x32_f16(qa0, bwf[1][0], tw1, 0, 0, 0);
        tw1 = __builtin_amdgcn_mfma_f32_16x16x32_f16(qa1, bwf[1][1], tw1, 0, 0, 0);

        // write per-wave gather tables with row-validity folded in (invalid rows = 0)
        #pragma unroll
        for (int rr = 0; rr < 4; ++rr) {
            int lrow = quad * 4 + rr;
            int grow = rt * 16 + lrow;
            bool rv = (grow >= VPT_) && (grow < LW_);
            th_t[lrow * 28 + n] = rv ? th0[rr] : 0.0f;
            tw_t[lrow * 28 + n] = rv ? tw0[rr] : 0.0f;
            if (n < 12) {
                th_t[lrow * 28 + 16 + n] = rv ? th1[rr] : 0.0f;
                tw_t[lrow * 28 + 16 + n] = rv ? tw1[rr] : 0.0f;
            }
        }

        // QK^T
        floatx4 s[13];
        #pragma unroll
        for (int ct = 0; ct < 13; ++ct) {
            half8 kb0 = *reinterpret_cast<const half8*>(&Ks[(ct * 16 + n) * 72 + quad * 8]);
            half8 kb1 = *reinterpret_cast<const half8*>(&Ks[(ct * 16 + n) * 72 + 32 + quad * 8]);
            floatx4 a = {};
            a = __builtin_amdgcn_mfma_f32_16x16x32_f16(qa0, kb0, a, 0, 0, 0);
            a = __builtin_amdgcn_mfma_f32_16x16x32_f16(qa1, kb1, a, 0, 0, 0);
            s[ct] = a;
        }

        // scale + rel bias (lean gather: row-mask already in tables)
        #pragma unroll
        for (int rr = 0; rr < 4; ++rr) {
            int row = rt * 16 + quad * 4 + rr;
            int q2 = row - VPT_; if (q2 < 0) q2 = 0;
            int qh = q2 / WSz, qw = q2 - qh * WSz;
            const float* pth = th_t + (quad * 4 + rr) * 28 + qh;
            const float* ptw = tw_t + (quad * 4 + rr) * 28 + qw;
            {   // ct = 0: keys 0..15; keys < VPT get no rel bias
                float tv = pth[oh[0]] + ptw[ow[0]];
                float sv = s[0][rr] * 0.125f;
                sv += (n >= VPT_) ? tv : 0.0f;
                s[0][rr] = sv;
            }
            #pragma unroll
            for (int ct = 1; ct < 12; ++ct) {
                float tv = pth[oh[ct]] + ptw[ow[ct]];
                s[ct][rr] = s[ct][rr] * 0.125f + tv;
            }
            {   // ct = 12: keys 192..207; n>=14 -> key>=206 masked
                float tv = pth[oh[12]] + ptw[ow[12]];
                float sv = s[12][rr] * 0.125f + tv;
                s[12][rr] = (n < 14) ? sv : -1e30f;
            }
        }

        // softmax over keys (lanes n within 16-group hold key tiles)
        float mx[4] = {-1e30f, -1e30f, -1e30f, -1e30f};
        #pragma unroll
        for (int ct = 0; ct < 13; ++ct)
            #pragma unroll
            for (int rr = 0; rr < 4; ++rr) mx[rr] = fmaxf(mx[rr], s[ct][rr]);
        #pragma unroll
        for (int rr = 0; rr < 4; ++rr)
            #pragma unroll
            for (int off = 1; off < 16; off <<= 1) mx[rr] = fmaxf(mx[rr], __shfl_xor(mx[rr], off));
        float sm[4] = {0.f, 0.f, 0.f, 0.f};
        #pragma unroll
        for (int ct = 0; ct < 13; ++ct)
            #pragma unroll
            for (int rr = 0; rr < 4; ++rr) {
                float p = __expf(s[ct][rr] - mx[rr]);
                s[ct][rr] = p; sm[rr] += p;
            }
        #pragma unroll
        for (int rr = 0; rr < 4; ++rr) {
            #pragma unroll
            for (int off = 1; off < 16; off <<= 1) sm[rr] += __shfl_xor(sm[rr], off);
            sm[rr] = 1.0f / sm[rr];
        }
        #pragma unroll
        for (int ct = 0; ct < 13; ++ct)
            #pragma unroll
            for (int rr = 0; rr < 4; ++rr) s[ct][rr] *= sm[rr];

        // PV: per 32-key block, one K=32 MFMA per d-tile (proven path)
        floatx4 o[4] = {};
        #pragma unroll
        for (int kt = 0; kt < 7; ++kt) {
            #pragma unroll
            for (int h2 = 0; h2 < 2; ++h2) {
                int ct = kt * 2 + h2;
                #pragma unroll
                for (int rr = 0; rr < 4; ++rr) {
                    float pv = (ct < 13) ? s[ct][rr] : 0.0f;
                    pcw[(quad * 4 + rr) * 40 + h2 * 16 + n] = (_Float16)pv;
                }
            }
            half8 pa = *reinterpret_cast<const half8*>(&pcw[n * 40 + quad * 8]);
            #pragma unroll
            for (int dt = 0; dt < 4; ++dt) {
                half8 vb = *reinterpret_cast<const half8*>(&Vt[(dt * 16 + n) * 232 + kt * 32 + quad * 8]);
                o[dt] = __builtin_amdgcn_mfma_f32_16x16x32_f16(pa, vb, o[dt], 0, 0, 0);
            }
        }

        // scatter stores: prompt rows -> attP, in-range spatial rows -> attS
        #pragma unroll
        for (int dt = 0; dt < 4; ++dt)
            #pragma unroll
            for (int rr = 0; rr < 4; ++rr) {
                int row = rt * 16 + quad * 4 + rr;
                if (row >= LW_) continue;
                _Float16 val = (_Float16)o[dt][rr];
                int col = hh * HDd + dt * 16 + n;
                if (row < VPT_) {
                    attP[((size_t)(bwi * VPT_ + row)) * Cc + col] = val;
                } else {
                    int g = rowOff[row];
                    if (g >= 0) attS[(size_t)g * Cc + col] = val;
                }
            }

        qa0 = nq0; qa1 = nq1;
    }
}

// ---------------- launcher ----------------
extern "C" void kernel_launch(void* const* d_in, const int* in_sizes, int n_in,
                              void* d_out, int out_size, void* d_ws, size_t ws_size,
                              hipStream_t stream)
{
    const float* x     = (const float*)d_in[0];
    const float* ln1w  = (const float*)d_in[1];
    const float* ln1b  = (const float*)d_in[2];
    const float* qkvw  = (const float*)d_in[3];
    const float* qkvb  = (const float*)d_in[4];
    const float* projw = (const float*)d_in[5];
    const float* projb = (const float*)d_in[6];
    const float* relh  = (const float*)d_in[7];
    const float* relw  = (const float*)d_in[8];
    const float* ln2w  = (const float*)d_in[9];
    const float* ln2b  = (const float*)d_in[10];
    const float* w1    = (const float*)d_in[11];
    const float* b1    = (const float*)d_in[12];
    const float* w2    = (const float*)d_in[13];
    const float* b2    = (const float*)d_in[14];
    float* out = (float*)d_out;
    char* ws = (char*)d_ws;

    // workspace layout (bytes); peak 228.8 MB (during QKV gemm)
    _Float16* wqkv_h  = (_Float16*)(ws + 0);          // 2304*768*2   = 3,538,944
    _Float16* wproj_h = (_Float16*)(ws + 3538944);    //  768*768*2   = 1,179,648
    _Float16* w1_h    = (_Float16*)(ws + 4718592);    // 3072*768*2   = 4,718,592
    _Float16* w2_h    = (_Float16*)(ws + 9437184);    //  768*3072*2  = 4,718,592
    _Float16* qkvb_h  = (_Float16*)(ws + 14155776);   // 2304*2       = 4,608
    _Float16* attP    = (_Float16*)(ws + 14160384);   // 200*10*768*2 = 3,072,000
    _Float16* tokA    = (_Float16*)(ws + 17232384);   // region A: 32848*768*2 = 50,454,528
    char* regB = ws + 77438976;
    _Float16* qkv_h  = (_Float16*)regB;               // 32848*2304*2 = 151,363,584 (dies after attn)
    _Float16* hbuf   = (_Float16*)regB;               // 16424*3072*2 = 100,909,056 (MLP phase)
    _Float16* x2h    = (_Float16*)(regB + 100909056); // 32848*768*2  = 50,454,528

    // 1. weights + qkv bias -> fp16 (single launch)
    {
        int na = 2304 * 768, nb = 768 * 768, nc = 3072 * 768, nd = 768 * 3072, ne = 2304;
        int tot = na + nb + nc + nd + ne;
        f2h_all_kernel<<<(tot + 255) / 256, 256, 0, stream>>>(
            qkvw, wqkv_h, na, projw, wproj_h, nb, w1, w1_h, nc, w2, w2_h, nd, qkvb, qkvb_h, ne);
    }
    // 2. LN1 (contiguous; no window scatter, no memset)
    ln1_kernel<<<Bb * Ll, 256, 0, stream>>>(x, ln1w, ln1b, tokA);
    // 3. QKV gemm on distinct rows only (M=32848, N=2304, K=768), grid 129x9
    gemm256<0><<<129 * 9, 512, 0, stream>>>(tokA, wqkv_h, qkvb, nullptr, nullptr, qkv_h, nullptr,
                                            32848, 2304, 768, 129, 9);
    // 4. MFMA attention (gathers windows via rowOff) -> attS (region A) + attP
    attn_mfma_kernel<<<BW_ * NHh, 256, 0, stream>>>(qkv_h, qkvb_h, relh, relw, tokA, attP);
    // 5. prompt mean over 25 windows -> attS rows l<10
    pmean_kernel<<<Bb * VPT_, 256, 0, stream>>>(attP, tokA);
    // 6. proj gemm (M=32848) fused with x2 = x + proj + bias (EPI 3) -> x2h fp16
    gemm256<3><<<129 * 3, 512, 0, stream>>>(tokA, wproj_h, projb, nullptr, x, x2h, nullptr,
                                            32848, 768, 768, 129, 3);
    // 7. LN2 -> xn2 (region A)
    ln2_kernel<<<Bb * Ll, 256, 0, stream>>>(x2h, ln2w, ln2b, tokA);
    // 8. MLP in 2 chunks of 16424 rows (hbuf reuses regB head; qkv dead by now)
    for (int ch = 0; ch < 2; ++ch) {
        size_t r0 = (size_t)ch * 16424;
        gemm256<1><<<65 * 12, 512, 0, stream>>>(tokA + r0 * 768, w1_h, b1, nullptr, nullptr, hbuf, nullptr,
                                                16424, 3072, 768, 65, 12);
        gemm256<2><<<65 * 3, 512, 0, stream>>>(hbuf, w2_h, b2, x2h + r0 * 768, nullptr, nullptr, out + r0 * 768,
                                               16424, 768, 3072, 65, 3);
    }
}